// Round 16
// baseline (246.334 us; speedup 1.0000x reference)
//
#include <hip/hip_runtime.h>
#include <hip/hip_bf16.h>

#define T_LEN 2048
#define BSZ 16
#define NHEAD 8
#define BH 128
#define NSEG 16
#define SC 128
#define MF 266
#define CH 96
#define PROWS 296
#define SROWS 65
#define CH_ELE (SROWS*96)      // 6240 u16 per chunk tile
#define SEG_ELE (3*CH_ELE)     // 18720 u16 per (bh,seg)
#define Z_OFF (64*96)          // z-row offset within chunk tile

constexpr float DN    = 0.3535533905932738f;    // 64^-0.25
constexpr float RATIO = 0.06131393394849658f;   // 266^-0.5
constexpr float EPSK  = 1e-4f;
constexpr float EPSD  = 1e-6f;
constexpr float QSC   = 0.125f;                 // 64^-0.5
constexpr float L2E   = 1.4426950408889634f;
constexpr float L2R   = -4.0276411511f;         // log2(RATIO)
constexpr float RB    = 6.131393394849658e-6f;  // RATIO*EPSK

typedef unsigned short u16;
typedef __attribute__((ext_vector_type(8))) short short8;
typedef __attribute__((ext_vector_type(4))) float f32x4;
typedef __attribute__((ext_vector_type(4))) unsigned short us4;

#define MFMA16(a,b,c) __builtin_amdgcn_mfma_f32_16x16x32_bf16(a,b,c,0,0,0)

__device__ __forceinline__ u16 f2bf(float f){
    union { __hip_bfloat16 h; u16 u; } cv;
    cv.h = __float2bfloat16(f);
    return cv.u;
}
__device__ __forceinline__ float bf2f(u16 u){ return __uint_as_float(((unsigned)u) << 16); }
__device__ __forceinline__ unsigned enc_f(float f){
    unsigned u = __float_as_uint(f);
    return (u & 0x80000000u) ? ~u : (u | 0x80000000u);
}
__device__ __forceinline__ float dec_f(unsigned u){
    unsigned b = (u & 0x80000000u) ? (u ^ 0x80000000u) : ~u;
    return __uint_as_float(b);
}

// async global->LDS copy of a CONTIGUOUS blob; 512 threads.
// LDS base per instruction is wave-uniform; HW adds lane*16.
__device__ __forceinline__ void gllds_copy(const void* gsrc, void* ldst, int nbytes, int tid)
{
    #pragma unroll
    for (int base = 0; base < 16384; base += 8192) {
        if (base >= nbytes) break;
        const int off = base + tid * 16;
        if (off < nbytes) {
            __builtin_amdgcn_global_load_lds(
                (const __attribute__((address_space(1))) unsigned int*)((const char*)gsrc + off),
                (__attribute__((address_space(3))) unsigned int*)((char*)ldst + base + (tid & ~63) * 16),
                16, 0, 0);
        }
    }
}

// ---------------- kernPJ: proj + Wq(padded per-head) + Wk/Wv/Wo -> bf16 ws ------------
__launch_bounds__(256)
__global__ void kernPJ(const float* __restrict__ proj,
                       const float* __restrict__ Wq, const float* __restrict__ Wk,
                       const float* __restrict__ Wv, const float* __restrict__ Wo,
                       u16* __restrict__ projb, u16* __restrict__ wqp,
                       u16* __restrict__ wkb, u16* __restrict__ wvb,
                       u16* __restrict__ wob_ws, unsigned* __restrict__ kmax_u)
{
    const int i = blockIdx.x * 256 + threadIdx.x;
    if (i == 0) *kmax_u = 0x007FFFFFu;                  // enc(-inf)
    if (i < PROWS * 9) {                                // proj -> [296][72]
        const int row = i / 9, gi = i % 9, c8 = gi * 8;
        us4 lo = (us4)0, hi = (us4)0;
        if (row < MF && gi < 8) {
            const float* s = proj + (size_t)row * 64 + c8;
            float4 x0 = *(const float4*)s, x1 = *(const float4*)(s + 4);
            lo[0]=f2bf(x0.x); lo[1]=f2bf(x0.y); lo[2]=f2bf(x0.z); lo[3]=f2bf(x0.w);
            hi[0]=f2bf(x1.x); hi[1]=f2bf(x1.y); hi[2]=f2bf(x1.z); hi[3]=f2bf(x1.w);
        }
        *(us4*)(projb + row * 72 + c8)     = lo;
        *(us4*)(projb + row * 72 + c8 + 4) = hi;
    } else if (i < PROWS * 9 + 4608) {                  // Wq -> [8][64][72] padded
        const int j = i - PROWS * 9;
        const int head = j / 576, rem = j % 576;
        const int r = rem / 9, gi = rem % 9, c8 = gi * 8;
        us4 lo = (us4)0, hi = (us4)0;
        if (gi < 8) {
            const float* s = Wq + ((size_t)(head * 64 + r)) * 64 + c8;
            float4 x0 = *(const float4*)s, x1 = *(const float4*)(s + 4);
            lo[0]=f2bf(x0.x); lo[1]=f2bf(x0.y); lo[2]=f2bf(x0.z); lo[3]=f2bf(x0.w);
            hi[0]=f2bf(x1.x); hi[1]=f2bf(x1.y); hi[2]=f2bf(x1.z); hi[3]=f2bf(x1.w);
        }
        *(us4*)(wqp + ((size_t)(head * 64 + r)) * 72 + c8)     = lo;
        *(us4*)(wqp + ((size_t)(head * 64 + r)) * 72 + c8 + 4) = hi;
    } else if (i < PROWS * 9 + 4608 + 2 * 4096) {       // Wk, Wv -> [512][64]
        const int j = i - (PROWS * 9 + 4608);
        const int mat = j >> 12;
        const int r = (j & 4095) >> 3, d8 = (j & 7) * 8;
        const float* W = (mat == 0) ? Wk : Wv;
        u16* dst       = (mat == 0) ? wkb : wvb;
        const float* s = W + (size_t)r * 64 + d8;
        float4 x0 = *(const float4*)s, x1 = *(const float4*)(s + 4);
        us4 lo, hi;
        lo[0]=f2bf(x0.x); lo[1]=f2bf(x0.y); lo[2]=f2bf(x0.z); lo[3]=f2bf(x0.w);
        hi[0]=f2bf(x1.x); hi[1]=f2bf(x1.y); hi[2]=f2bf(x1.z); hi[3]=f2bf(x1.w);
        *(us4*)(dst + (size_t)r * 64 + d8)     = lo;
        *(us4*)(dst + (size_t)r * 64 + d8 + 4) = hi;
    } else if (i < PROWS * 9 + 4608 + 3 * 4096) {       // Wo: 64 rows x 512 cols
        const int j = i - (PROWS * 9 + 4608 + 2 * 4096);
        const int r = j >> 6, c8 = (j & 63) * 8;
        const float* s = Wo + (size_t)r * 512 + c8;
        float4 x0 = *(const float4*)s, x1 = *(const float4*)(s + 4);
        us4 lo, hi;
        lo[0]=f2bf(x0.x); lo[1]=f2bf(x0.y); lo[2]=f2bf(x0.z); lo[3]=f2bf(x0.w);
        hi[0]=f2bf(x1.x); hi[1]=f2bf(x1.y); hi[2]=f2bf(x1.z); hi[3]=f2bf(x1.w);
        *(us4*)(wob_ws + (size_t)r * 512 + c8)     = lo;
        *(us4*)(wob_ws + (size_t)r * 512 + c8 + 4) = hi;
    }
}

// bf16 tile copy (kernH): src rows (64 wide) -> LDS [nrows][72]
__device__ __forceinline__ void copy_rows72(const u16* __restrict__ src, u16* dst,
                                            int m0, int nrows, int tid, int nthr)
{
    for (int i = tid; i < nrows * 8; i += nthr) {
        int mi = i >> 3, d8 = (i & 7) * 8;
        *(short8*)(dst + mi * 72 + d8) =
            *(const short8*)(src + (size_t)(m0 + mi) * 64 + d8);
    }
}

// ---------------- kernH: k,v head projections -> bf16 ws (+ diag for k) --------------
__launch_bounds__(256)
__global__ void kernH(const float* __restrict__ kin, const float* __restrict__ vin,
                      const u16* __restrict__ wkb, const float* __restrict__ bk,
                      const u16* __restrict__ wvb, const float* __restrict__ bv,
                      u16* __restrict__ kh, u16* __restrict__ vh,
                      float* __restrict__ dkw)
{
    extern __shared__ char smh[];
    u16*   xb   = (u16*)smh;             // [128][72]  18432
    u16*   wb   = (u16*)(smh + 18432);   // [64][72]    9216
    float* bsh  = (float*)(smh + 27648); // [64]         256
    u16*   hout = (u16*)(smh + 27904);   // [128][72]  18432  -> 46336

    const int tid = threadIdx.x;
    const int iv  = blockIdx.y;                         // 0 = k, 1 = v
    const int r0  = blockIdx.x * 128;
    const float* src  = (iv == 0) ? kin : vin;
    const u16*   Wb   = (iv == 0) ? wkb : wvb;
    const float* bias = (iv == 0) ? bk  : bv;
    u16*   outp  = (iv == 0) ? kh : vh;
    float* diagp = (iv == 0) ? dkw : nullptr;
    const float scale = (iv == 0) ? DN : 1.0f;

    for (int i = tid; i < 128 * 8; i += 256) {
        int r = i >> 3, d8 = (i & 7) * 8;
        const float* s = src + (size_t)(r0 + r) * 64 + d8;
        float4 x0 = *(const float4*)s, x1 = *(const float4*)(s + 4);
        us4 lo, hi;
        lo[0]=f2bf(x0.x); lo[1]=f2bf(x0.y); lo[2]=f2bf(x0.z); lo[3]=f2bf(x0.w);
        hi[0]=f2bf(x1.x); hi[1]=f2bf(x1.y); hi[2]=f2bf(x1.z); hi[3]=f2bf(x1.w);
        *(us4*)(xb + r * 72 + d8)     = lo;
        *(us4*)(xb + r * 72 + d8 + 4) = hi;
    }

    const int c = tid & 15, g = (tid >> 4) & 3, w = tid >> 6;

    for (int h = 0; h < NHEAD; ++h) {
        __syncthreads();
        copy_rows72(Wb, wb, h * 64, 64, tid, 256);
        if (tid < 64) bsh[tid] = bias[h * 64 + tid];
        __syncthreads();

        #pragma unroll
        for (int mi = 0; mi < 2; ++mi) {
            const int mt = w * 2 + mi;
            short8 a0 = *(const short8*)(xb + (mt * 16 + c) * 72 + g * 8);
            short8 a1 = *(const short8*)(xb + (mt * 16 + c) * 72 + 32 + g * 8);
            float sq[4] = {0.f, 0.f, 0.f, 0.f};
            #pragma unroll
            for (int nt = 0; nt < 4; ++nt) {
                short8 b0 = *(const short8*)(wb + (nt * 16 + c) * 72 + g * 8);
                short8 b1 = *(const short8*)(wb + (nt * 16 + c) * 72 + 32 + g * 8);
                f32x4 acc = 0;
                acc = MFMA16(a0, b0, acc);
                acc = MFMA16(a1, b1, acc);
                const float bv2 = bsh[nt * 16 + c];
                #pragma unroll
                for (int r = 0; r < 4; ++r) {
                    float y = (acc[r] + bv2) * scale;
                    sq[r] = fmaf(y, y, sq[r]);
                    hout[(mt * 16 + g * 4 + r) * 72 + nt * 16 + c] = f2bf(y);
                }
            }
            if (diagp) {
                #pragma unroll
                for (int r = 0; r < 4; ++r) {
                    #pragma unroll
                    for (int off = 1; off < 16; off <<= 1) sq[r] += __shfl_xor(sq[r], off);
                    if (c == 0) {
                        int rr = r0 + mt * 16 + g * 4 + r;
                        int t = rr >> 4, bbb = rr & 15;
                        diagp[((size_t)(bbb * 8 + h)) * T_LEN + t] = 0.5f * sq[r];
                    }
                }
            }
        }
        __syncthreads();
        for (int i = tid; i < 128 * 8; i += 256) {
            int r = i >> 3, d8 = (i & 7) * 8;
            int rr = r0 + r, t = rr >> 4, bbb = rr & 15;
            *(short8*)(outp + ((size_t)(bbb * 8 + h) * T_LEN + t) * 64 + d8) =
                *(const short8*)(hout + r * 72 + d8);
        }
    }
}

// ---------------- kernA: unnormalized SsegT (chunk-major) + kmax; gllds staging -------
__launch_bounds__(512, 4)
__global__ void kernA(const u16* __restrict__ kh, const u16* __restrict__ vh,
                      const float* __restrict__ diagk, const u16* __restrict__ projb,
                      unsigned* __restrict__ kmax_u, u16* __restrict__ SsegT)
{
    extern __shared__ char sma[];
    u16* khb = (u16*)sma;            // [128][64] 16384 (gllds, contiguous)
    u16* vTb = (u16*)(sma + 16384);  // [80][136] 21760
    u16* pjb = (u16*)(sma + 38144);  // [96+][72] 14336 (gllds)
    u16* kfT = (u16*)(sma + 52480);  // [96][136] 26112   -> 78592
    __shared__ float red[8];

    const int tid = threadIdx.x;
    const int bh = blockIdx.x, seg = blockIdx.y, t0 = seg * SC;
    const int c = tid & 15, g = (tid >> 4) & 3, w = tid >> 6;
    const size_t sbN = ((size_t)bh * NSEG + seg) * SEG_ELE;
    const size_t hbase = ((size_t)bh * T_LEN + t0) * 64;

    gllds_copy(kh + hbase, khb, 16384, tid);
    gllds_copy(projb, pjb, 14336, tid);

    // vT transpose (vectorized reads): vT[e][s] = vh[t0+s][e]; row 64 = ones; 65..79 = 0
    for (int i = tid; i < 128 * 8; i += 512) {
        int s = i >> 3, e8 = (i & 7) * 8;
        short8 vv = *(const short8*)(vh + hbase + (size_t)s * 64 + e8);
        #pragma unroll
        for (int j = 0; j < 8; ++j) vTb[(e8 + j) * 136 + s] = (u16)vv[j];
    }
    if (tid < 128) vTb[64 * 136 + tid] = 0x3F80;   // bf16(1.0)
    for (int i = tid; i < 15 * 128; i += 512) {
        int r = i >> 7, s = i & 127;
        vTb[(65 + r) * 136 + s] = 0;
    }
    float dk2[4];
    #pragma unroll
    for (int r = 0; r < 4; ++r)
        dk2[r] = -diagk[(size_t)bh * T_LEN + t0 + w * 16 + g * 4 + r] * L2E;  // no kmax
    __syncthreads();                                 // khb/pjb(0) landed; vTb visible

    short8 ak0 = *(const short8*)(khb + (w * 16 + c) * 64 + g * 8);
    short8 ak1 = *(const short8*)(khb + (w * 16 + c) * 64 + 32 + g * 8);

    float kmx = -3.0e38f;

    for (int ch = 0; ch < 3; ++ch) {
        const int mbase = ch * CH;
        // eu features -> kfT (transposed); m==MF -> 1; other m>=MF -> 0; track dd max
        #pragma unroll
        for (int nt = 0; nt < 6; ++nt) {
            short8 b0 = *(const short8*)(pjb + (nt * 16 + c) * 72 + g * 8);
            short8 b1 = *(const short8*)(pjb + (nt * 16 + c) * 72 + 32 + g * 8);
            f32x4 dd = 0;
            dd = MFMA16(ak0, b0, dd);
            dd = MFMA16(ak1, b1, dd);
            const int m = mbase + nt * 16 + c;
            us4 kw;
            #pragma unroll
            for (int r = 0; r < 4; ++r) {
                float eu = __builtin_amdgcn_exp2f(fmaf(dd[r], L2E, dk2[r]));
                float kv = (m < MF) ? eu : ((m == MF) ? 1.0f : 0.f);
                kw[r] = f2bf(kv);
            }
            if (m < MF)
                kmx = fmaxf(kmx, fmaxf(fmaxf(dd[0], dd[1]), fmaxf(dd[2], dd[3])));
            *(us4*)(kfT + (nt * 16 + c) * 136 + w * 16 + g * 4) = kw;
        }
        __syncthreads();                             // kfT visible
        if (ch < 2)                                  // pjb dead -> async next chunk
            gllds_copy(projb + (size_t)(ch + 1) * CH * 72, pjb, 14336, tid);
        // D[m][e] = sum_s kfT[m][s] * vT[e][s]; store chunk-major [65][96]
        for (int tt = w; tt < 30; tt += 8) {
            const int mt = tt / 5, nt = tt % 5;
            f32x4 acc = 0;
            #pragma unroll
            for (int ks = 0; ks < 4; ++ks) {
                short8 a = *(const short8*)(kfT + (mt * 16 + c) * 136 + ks * 32 + g * 8);
                short8 b = *(const short8*)(vTb + (nt * 16 + c) * 136 + ks * 32 + g * 8);
                acc = MFMA16(a, b, acc);
            }
            const int e = nt * 16 + c;
            const int mloc = mt * 16 + g * 4;
            if (e <= 64) {
                us4 sw;
                #pragma unroll
                for (int r = 0; r < 4; ++r) sw[r] = f2bf(acc[r]);
                *(us4*)(SsegT + sbN + (size_t)ch * CH_ELE + (size_t)e * 96 + mloc) = sw;
            }
        }
        if (ch < 2) __syncthreads();                 // kfT reads done; pjb(ch+1) landed
    }

    // kmax reduction
    #pragma unroll
    for (int off = 1; off < 64; off <<= 1) kmx = fmaxf(kmx, __shfl_xor(kmx, off));
    if ((tid & 63) == 0) red[w] = kmx;
    __syncthreads();
    if (tid == 0) {
        float m8 = red[0];
        #pragma unroll
        for (int j = 1; j < 8; ++j) m8 = fmaxf(m8, red[j]);
        atomicMax(kmax_u, enc_f(m8));
    }
}

// ---------------- kernB: exclusive prefix + NORMALIZE (chunk-major layout) ------------
__launch_bounds__(512)
__global__ void kernB(u16* __restrict__ SsegT, const unsigned* __restrict__ kmax_u)
{
    __shared__ float vsl[NSEG][33];
    const int tid = threadIdx.x;
    const int bh = blockIdx.x, eh = blockIdx.y;
    const int nrows = eh ? 33 : 32;
    const int per_ch = nrows * 12;
    const int nch = 3 * per_ch;
    const float kmax = dec_f(*kmax_u);
    const float alpha = RATIO * __builtin_amdgcn_exp2f(-kmax * L2E);
    const float beta  = RATIO * EPSK;

    // pre-load raw Vsum column (chunk 2, mloc 74) for all segments BEFORE any write
    for (int i = tid; i < NSEG * nrows; i += 512) {
        const int s = i / nrows, er = i % nrows;
        vsl[s][er] = bf2f(SsegT[((size_t)bh * NSEG + s) * SEG_ELE + 2 * CH_ELE
                                + (size_t)(eh * 32 + er) * 96 + 74]);
    }
    __syncthreads();

    int idxs[3] = { tid, tid + 512, tid + 1024 };
    int chs[3], ers[3], m8s[3];
    bool act[3];
    #pragma unroll
    for (int k = 0; k < 3; ++k) {
        act[k] = idxs[k] < nch;
        int id = act[k] ? idxs[k] : 0;
        chs[k] = id / per_ch;
        int rem = id % per_ch;
        ers[k] = rem / 12;
        m8s[k] = (rem % 12) * 8;
    }
    float A0[8], A1[8], A2[8];
    float V0 = 0.f, V1 = 0.f, V2 = 0.f;
    #pragma unroll
    for (int j = 0; j < 8; ++j) { A0[j] = 0.f; A1[j] = 0.f; A2[j] = 0.f; }

    for (int s = 0; s < NSEG; ++s) {
        const size_t segb = ((size_t)bh * NSEG + s) * SEG_ELE;
        {
            const size_t gi = segb + (size_t)chs[0] * CH_ELE
                              + (size_t)(eh * 32 + ers[0]) * 96 + m8s[0];
            short8 v = *(const short8*)(SsegT + gi);
            short8 o;
            const float bv = beta * V0;
            #pragma unroll
            for (int j = 0; j < 8; ++j) {
                o[j] = (short)f2bf(fmaf(alpha, A0[j], bv));
                A0[j] += bf2f((u16)v[j]);
            }
            *(short8*)(SsegT + gi) = o;
            V0 += vsl[s][ers[0]];
        }
        if (act[1]) {
            const size_t gi = segb + (size_t)chs[1] * CH_ELE
                              + (size_t)(eh * 32 + ers[1]) * 96 + m8s[1];
            short8 v = *(const short8*)(SsegT + gi);
            short8 o;
            const float bv = beta * V1;
            #pragma unroll
            for (int j = 0; j < 8; ++j) {
                o[j] = (short)f2bf(fmaf(alpha, A1[j], bv));
                A1[j] += bf2f((u16)v[j]);
            }
            *(short8*)(SsegT + gi) = o;
            V1 += vsl[s][ers[1]];
        }
        if (act[2]) {
            const size_t gi = segb + (size_t)chs[2] * CH_ELE
                              + (size_t)(eh * 32 + ers[2]) * 96 + m8s[2];
            short8 v = *(const short8*)(SsegT + gi);
            short8 o;
            const float bv = beta * V2;
            #pragma unroll
            for (int j = 0; j < 8; ++j) {
                o[j] = (short)f2bf(fmaf(alpha, A2[j], bv));
                A2[j] += bf2f((u16)v[j]);
            }
            *(short8*)(SsegT + gi) = o;
            V2 += vsl[s][ers[2]];
        }
    }
}

// ---------------- kernC: main attention + fused q-projection (phase Q) ---------------
__launch_bounds__(512, 4)
__global__ void kernC(const float* __restrict__ qin, const float* __restrict__ bq,
                      const u16* __restrict__ wqp,
                      const u16* __restrict__ kh, const u16* __restrict__ vh,
                      const float* __restrict__ diagk,
                      const u16* __restrict__ projb, const u16* __restrict__ SsegT,
                      const unsigned* __restrict__ kmax_u, u16* __restrict__ merged)
{
    extern __shared__ char smc[];
    u16*   qfb = (u16*)smc;               // [128][104] 26624
    u16*   kfb = (u16*)(smc + 26624);     // [128][104] 26624 -> 53248
    u16*   pjc = (u16*)(smc + 53248);     // [96+][72]  14336 (gllds) -> 67584
    u16*   STb = (u16*)(smc + 67584);     // [64][96]   12288 (gllds) -> 79872
    float* zsf = (float*)(smc + 79872);   // [320] f32   1280 -> 81152
    u16*   wqt = kfb;                     // alias: [64][72] 9216 (phase Q only)
    u16*   Ab  = (u16*)smc;               // alias: [128][136] 34816
    u16*   vTb = (u16*)(smc + 34816);     // alias: [64][136] 17408 (within qfb/kfb)

    const int tid = threadIdx.x;
    const int bh = blockIdx.x, seg = blockIdx.y;
    const int bb = bh >> 3, hh = bh & 7;
    const int t0 = seg * SC;
    const int c = tid & 15, g = (tid >> 4) & 3, w = tid >> 6;
    const size_t hbase = ((size_t)bh * T_LEN + t0) * 64;
    const size_t sbN = ((size_t)bh * NSEG + seg) * SEG_ELE;
    const float kmax = dec_f(*kmax_u);
    const int arow = w * 16 + c;

    // async chunk-0 tiles + per-head Wq tile (into kfb region, dead until k-staging)
    gllds_copy(projb, pjc, 14336, tid);
    gllds_copy(SsegT + sbN, STb, 12288, tid);
    gllds_copy(wqp + (size_t)hh * 64 * 72, wqt, 9216, tid);

    // phase-Q A fragments: load q rows direct from qin (L3-hot) and convert in-register
    const float* qsrc = qin + ((size_t)(t0 + arow) * (BSZ * 64) + bb * 64);
    float4 qx0 = *(const float4*)(qsrc + g * 8);
    float4 qx1 = *(const float4*)(qsrc + g * 8 + 4);
    float4 qx2 = *(const float4*)(qsrc + 32 + g * 8);
    float4 qx3 = *(const float4*)(qsrc + 32 + g * 8 + 4);
    short8 a0q, a1q;
    a0q[0]=(short)f2bf(qx0.x); a0q[1]=(short)f2bf(qx0.y); a0q[2]=(short)f2bf(qx0.z); a0q[3]=(short)f2bf(qx0.w);
    a0q[4]=(short)f2bf(qx1.x); a0q[5]=(short)f2bf(qx1.y); a0q[6]=(short)f2bf(qx1.z); a0q[7]=(short)f2bf(qx1.w);
    a1q[0]=(short)f2bf(qx2.x); a1q[1]=(short)f2bf(qx2.y); a1q[2]=(short)f2bf(qx2.z); a1q[3]=(short)f2bf(qx2.w);
    a1q[4]=(short)f2bf(qx3.x); a1q[5]=(short)f2bf(qx3.y); a1q[6]=(short)f2bf(qx3.z); a1q[7]=(short)f2bf(qx3.w);

    // z rows (f32, pre-biased with EPSD) + dk2
    if (tid < 288) {
        int chz = tid / 96, ml = tid % 96;
        zsf[tid] = bf2f(SsegT[sbN + (size_t)chz * CH_ELE + Z_OFF + ml]) + EPSD;
    } else if (tid < 320) {
        zsf[tid] = 0.f;
    }
    float dk2[4];
    #pragma unroll
    for (int r = 0; r < 4; ++r) {
        const size_t t = (size_t)bh * T_LEN + t0 + w * 16 + g * 4 + r;
        dk2[r] = fmaf(-(diagk[t] + kmax), L2E, L2R);
    }
    __syncthreads();                                 // bar1: wqt/pjc0/STb0 landed; zsf visible

    // phase Q: q-head projection (8 MFMA) -> qfb cols 0..63; diag_q inline -> dq2
    float dq2[4];
    {
        float sq[4] = {0.f, 0.f, 0.f, 0.f};
        #pragma unroll
        for (int nt = 0; nt < 4; ++nt) {
            short8 b0 = *(const short8*)(wqt + (nt * 16 + c) * 72 + g * 8);
            short8 b1 = *(const short8*)(wqt + (nt * 16 + c) * 72 + 32 + g * 8);
            f32x4 acc = 0;
            acc = MFMA16(a0q, b0, acc);
            acc = MFMA16(a1q, b1, acc);
            const float bv2 = bq[hh * 64 + nt * 16 + c];
            #pragma unroll
            for (int r = 0; r < 4; ++r) {
                float y = (acc[r] + bv2) * (QSC * DN);
                sq[r] = fmaf(y, y, sq[r]);
                qfb[(w * 16 + g * 4 + r) * 104 + nt * 16 + c] = f2bf(y);
            }
        }
        #pragma unroll
        for (int r = 0; r < 4; ++r) {
            #pragma unroll
            for (int off = 1; off < 16; off <<= 1) sq[r] += __shfl_xor(sq[r], off);
            dq2[r] = fmaf(-0.5f * sq[r], L2E, L2R);  // no q-max (validated R5-R15)
        }
    }
    __syncthreads();                                 // bar2: qfb written; wqt dead

    // stage k into kfb (coalesced)
    for (int i = tid; i < 128 * 8; i += 512) {
        int r = i >> 3, d8 = (i & 7) * 8;
        *(short8*)(kfb + r * 104 + d8) = *(const short8*)(kh + hbase + (size_t)r * 64 + d8);
    }
    __syncthreads();                                 // bar3: q/k head tiles ready
    short8 aq0 = *(const short8*)(qfb + arow * 104 + g * 8);
    short8 aq1 = *(const short8*)(qfb + arow * 104 + 32 + g * 8);
    short8 ak0 = *(const short8*)(kfb + arow * 104 + g * 8);
    short8 ak1 = *(const short8*)(kfb + arow * 104 + 32 + g * 8);

    f32x4 Aacc[8], nacc[4];
    #pragma unroll
    for (int nt = 0; nt < 8; ++nt) Aacc[nt] = 0;
    #pragma unroll
    for (int nt = 0; nt < 4; ++nt) nacc[nt] = 0;
    float pden[4] = {0.f, 0.f, 0.f, 0.f};

    for (int ch = 0; ch < 3; ++ch) {
        const int mb0 = ch * CH;
        if (ch > 0)                                 // STb(ch-1) reads done at loop-end barrier
            gllds_copy(SsegT + sbN + (size_t)ch * CH_ELE, STb, 12288, tid);
        // features (writes qfb/kfb) + den-partial (pre-biased z from LDS f32)
        #pragma unroll
        for (int nt = 0; nt < 6; ++nt) {
            const int m = mb0 + nt * 16 + c;
            short8 b0 = *(const short8*)(pjc + (nt * 16 + c) * 72 + g * 8);
            short8 b1 = *(const short8*)(pjc + (nt * 16 + c) * 72 + 32 + g * 8);
            f32x4 ddq = 0, ddk = 0;
            ddq = MFMA16(aq0, b0, ddq); ddq = MFMA16(aq1, b1, ddq);
            ddk = MFMA16(ak0, b0, ddk); ddk = MFMA16(ak1, b1, ddk);
            const float zl = zsf[m];
            #pragma unroll
            for (int r = 0; r < 4; ++r) {
                float qv = __builtin_amdgcn_exp2f(fmaf(ddq[r], L2E, dq2[r])) + RB;
                float kv = __builtin_amdgcn_exp2f(fmaf(ddk[r], L2E, dk2[r])) + RB;
                if (m >= MF) { qv = 0.f; kv = 0.f; }
                pden[r] = fmaf(qv, zl, pden[r]);
                const int row = w * 16 + g * 4 + r;
                qfb[row * 104 + nt * 16 + c] = f2bf(qv);
                kfb[row * 104 + nt * 16 + c] = f2bf(kv);
            }
        }
        __syncthreads();                            // features visible; STb(ch) landed
        if (ch < 2)                                 // pjc(ch) dead -> async next chunk
            gllds_copy(projb + (size_t)(ch + 1) * CH * 72, pjc, 14336, tid);
        short8 af[3];
        #pragma unroll
        for (int ks = 0; ks < 3; ++ks)
            af[ks] = *(const short8*)(qfb + arow * 104 + ks * 32 + g * 8);
        #pragma unroll
        for (int nt = 0; nt < 8; ++nt) {
            #pragma unroll
            for (int ks = 0; ks < 3; ++ks) {
                short8 b = *(const short8*)(kfb + (nt * 16 + c) * 104 + ks * 32 + g * 8);
                Aacc[nt] = MFMA16(af[ks], b, Aacc[nt]);
            }
        }
        #pragma unroll
        for (int nt = 0; nt < 4; ++nt) {
            #pragma unroll
            for (int ks = 0; ks < 3; ++ks) {
                short8 b = *(const short8*)(STb + (nt * 16 + c) * 96 + ks * 32 + g * 8);
                nacc[nt] = MFMA16(af[ks], b, nacc[nt]);
            }
        }
        if (ch < 2) __syncthreads();                // GEMM LDS reads done; pjc(ch+1) landed
    }

    // den = qf.(z_pre+EPSD) + rowsum(masked A)
    float den[4], rs[4] = {0.f, 0.f, 0.f, 0.f};
    #pragma unroll
    for (int r = 0; r < 4; ++r) {
        #pragma unroll
        for (int off = 1; off < 16; off <<= 1) pden[r] += __shfl_xor(pden[r], off);
        den[r] = pden[r];
    }
    #pragma unroll
    for (int nt = 0; nt < 8; ++nt) {
        #pragma unroll
        for (int r = 0; r < 4; ++r) {
            const int row = w * 16 + g * 4 + r, sc2 = nt * 16 + c;
            float av = (sc2 < row) ? Aacc[nt][r] : 0.f;
            Aacc[nt][r] = av;
            rs[r] += av;
        }
    }
    #pragma unroll
    for (int r = 0; r < 4; ++r) {
        #pragma unroll
        for (int off = 1; off < 16; off <<= 1) rs[r] += __shfl_xor(rs[r], off);
        den[r] += rs[r];
    }

    __syncthreads();                                // all chunk reads done
    #pragma unroll
    for (int nt = 0; nt < 8; ++nt)
        #pragma unroll
        for (int r = 0; r < 4; ++r)
            Ab[(w * 16 + g * 4 + r) * 136 + nt * 16 + c] = f2bf(Aacc[nt][r]);
    for (int i = tid; i < 128 * 8; i += 512) {
        int s = i >> 3, e8 = (i & 7) * 8;
        short8 vv = *(const short8*)(vh + hbase + (size_t)s * 64 + e8);
        #pragma unroll
        for (int j = 0; j < 8; ++j) vTb[(e8 + j) * 136 + s] = (u16)vv[j];
    }
    __syncthreads();

    short8 aab[4];
    #pragma unroll
    for (int ks = 0; ks < 4; ++ks)
        aab[ks] = *(const short8*)(Ab + arow * 136 + ks * 32 + g * 8);
    #pragma unroll
    for (int nt = 0; nt < 4; ++nt) {
        #pragma unroll
        for (int ks = 0; ks < 4; ++ks) {
            short8 b = *(const short8*)(vTb + (nt * 16 + c) * 136 + ks * 32 + g * 8);
            nacc[nt] = MFMA16(aab[ks], b, nacc[nt]);
        }
    }

    #pragma unroll
    for (int r = 0; r < 4; ++r) {
        const float inv = 1.0f / den[r];
        const int t = t0 + w * 16 + g * 4 + r;
        #pragma unroll
        for (int nt = 0; nt < 4; ++nt)
            merged[((size_t)bb * T_LEN + t) * 512 + hh * 64 + nt * 16 + c] =
                f2bf(nacc[nt][r] * inv);
    }
}

// ---------------- kernD: output projection + transpose (bf16 Wo from ws) --------------
__launch_bounds__(256)
__global__ void kernD(const u16* __restrict__ merged, const u16* __restrict__ wob_ws,
                      const float* __restrict__ bo, float* __restrict__ out)
{
    extern __shared__ char smd[];
    u16* mb  = (u16*)smd;            // [128][136] 34816
    u16* wob = (u16*)(smd + 34816);  // [64][136]  17408

    const int tid = threadIdx.x;
    const int r0 = blockIdx.x * 128;
    const int c = tid & 15, g = (tid >> 4) & 3, w = tid >> 6;

    f32x4 acc[2][4];
    #pragma unroll
    for (int mi = 0; mi < 2; ++mi)
        #pragma unroll
        for (int nt = 0; nt < 4; ++nt) acc[mi][nt] = 0;

    for (int kc = 0; kc < 4; ++kc) {
        __syncthreads();
        for (int i = tid; i < 128 * 16; i += 256) {
            int r = i >> 4, d8 = (i & 15) * 8;
            *(short8*)(mb + r * 136 + d8) =
                *(const short8*)(merged + (size_t)(r0 + r) * 512 + kc * 128 + d8);
        }
        for (int i = tid; i < 64 * 16; i += 256) {
            int r = i >> 4, d8 = (i & 15) * 8;
            *(short8*)(wob + r * 136 + d8) =
                *(const short8*)(wob_ws + (size_t)r * 512 + kc * 128 + d8);
        }
        __syncthreads();
        #pragma unroll
        for (int mi = 0; mi < 2; ++mi) {
            const int mt = w * 2 + mi;
            #pragma unroll
            for (int ks = 0; ks < 4; ++ks) {
                short8 a = *(const short8*)(mb + (mt * 16 + c) * 136 + ks * 32 + g * 8);
                #pragma unroll
                for (int nt = 0; nt < 4; ++nt) {
                    short8 b = *(const short8*)(wob + (nt * 16 + c) * 136 + ks * 32 + g * 8);
                    acc[mi][nt] = MFMA16(a, b, acc[mi][nt]);
                }
            }
        }
    }
    #pragma unroll
    for (int mi = 0; mi < 2; ++mi) {
        const int mt = w * 2 + mi;
        #pragma unroll
        for (int nt = 0; nt < 4; ++nt) {
            const float bv2 = bo[nt * 16 + c];
            #pragma unroll
            for (int r = 0; r < 4; ++r) {
                int rg = r0 + mt * 16 + g * 4 + r;
                int bbb = rg >> 11, t = rg & (T_LEN - 1);
                out[((size_t)t * BSZ + bbb) * 64 + nt * 16 + c] = acc[mi][nt][r] + bv2;
            }
        }
    }
}

extern "C" void kernel_launch(void* const* d_in, const int* in_sizes, int n_in,
                              void* d_out, int out_size, void* d_ws, size_t ws_size,
                              hipStream_t stream)
{
    (void)in_sizes; (void)n_in; (void)out_size; (void)ws_size;
    const float* qin  = (const float*)d_in[0];
    const float* kin  = (const float*)d_in[1];
    const float* vin  = (const float*)d_in[2];
    const float* Wq   = (const float*)d_in[3];
    const float* bq   = (const float*)d_in[4];
    const float* Wk   = (const float*)d_in[5];
    const float* bk   = (const float*)d_in[6];
    const float* Wv   = (const float*)d_in[7];
    const float* bv   = (const float*)d_in[8];
    const float* Wo   = (const float*)d_in[9];
    const float* bo   = (const float*)d_in[10];
    const float* proj = (const float*)d_in[11];

    char* p = (char*)d_ws;
    unsigned* kmax_u = (unsigned*)p;           p += 256;
    u16* projb = (u16*)p;  p += (size_t)PROWS * 72 * 2;                 // 42,624 B
    u16* wqp = (u16*)p;    p += (size_t)8 * 64 * 72 * 2;                // 73,728 B padded
    u16* wkb = (u16*)p;    p += (size_t)512 * 64 * 2;
    u16* wvb = (u16*)p;    p += (size_t)512 * 64 * 2;
    u16* wob_ws = (u16*)p; p += (size_t)64 * 512 * 2;
    u16* kh_ws = (u16*)p;  p += (size_t)BH * T_LEN * 64 * 2;
    u16* vh_ws = (u16*)p;  p += (size_t)BH * T_LEN * 64 * 2;
    float* diagk = (float*)p; p += (size_t)BH * T_LEN * 4;
    u16* SsegT = (u16*)p;  p += (size_t)BH * NSEG * SEG_ELE * 2 + 1024;  // 76.7 MB
    u16* merged = (u16*)p;                                               // 33.5 MB

    const int LDS_H = 46336;
    const int LDS_A = 78592;
    const int LDS_C = 81152;
    const int LDS_D = 52224;
    (void)hipFuncSetAttribute((const void*)kernA, hipFuncAttributeMaxDynamicSharedMemorySize, LDS_A);
    (void)hipFuncSetAttribute((const void*)kernC, hipFuncAttributeMaxDynamicSharedMemorySize, LDS_C);

    kernPJ<<<77, 256, 0, stream>>>(proj, Wq, Wk, Wv, Wo, projb, wqp, wkb, wvb, wob_ws, kmax_u);
    kernH<<<dim3(256, 2), 256, LDS_H, stream>>>(kin, vin, wkb, bk, wvb, bv,
                                                kh_ws, vh_ws, diagk);
    kernA<<<dim3(BH, NSEG), 512, LDS_A, stream>>>(kh_ws, vh_ws, diagk, projb, kmax_u, SsegT);
    kernB<<<dim3(BH, 2), 512, 0, stream>>>(SsegT, kmax_u);
    kernC<<<dim3(BH, NSEG), 512, LDS_C, stream>>>(qin, bq, wqp, kh_ws, vh_ws, diagk,
                                                  projb, SsegT, kmax_u, merged);
    kernD<<<256, 256, LDS_D, stream>>>(merged, wob_ws, bo, (float*)d_out);
}

// Round 17
// 233.345 us; speedup vs baseline: 1.0557x; 1.0557x over previous
//
#include <hip/hip_runtime.h>
#include <hip/hip_bf16.h>

#define T_LEN 2048
#define BSZ 16
#define NHEAD 8
#define BH 128
#define NSEG 16
#define SC 128
#define MF 266
#define CH 96
#define PROWS 296
#define SROWS 65
#define CH_ELE (SROWS*96)      // 6240 u16 per chunk tile
#define SEG_ELE (3*CH_ELE)     // 18720 u16 per (bh,seg)
#define Z_OFF (64*96)          // z-row offset within chunk tile

constexpr float DN    = 0.3535533905932738f;    // 64^-0.25
constexpr float RATIO = 0.06131393394849658f;   // 266^-0.5
constexpr float EPSK  = 1e-4f;
constexpr float EPSD  = 1e-6f;
constexpr float QSC   = 0.125f;                 // 64^-0.5
constexpr float L2E   = 1.4426950408889634f;
constexpr float L2R   = -4.0276411511f;         // log2(RATIO)
constexpr float RB    = 6.131393394849658e-6f;  // RATIO*EPSK

typedef unsigned short u16;
typedef __attribute__((ext_vector_type(8))) short short8;
typedef __attribute__((ext_vector_type(4))) float f32x4;
typedef __attribute__((ext_vector_type(4))) unsigned short us4;

#define MFMA16(a,b,c) __builtin_amdgcn_mfma_f32_16x16x32_bf16(a,b,c,0,0,0)

__device__ __forceinline__ u16 f2bf(float f){
    union { __hip_bfloat16 h; u16 u; } cv;
    cv.h = __float2bfloat16(f);
    return cv.u;
}
__device__ __forceinline__ float bf2f(u16 u){ return __uint_as_float(((unsigned)u) << 16); }
__device__ __forceinline__ unsigned enc_f(float f){
    unsigned u = __float_as_uint(f);
    return (u & 0x80000000u) ? ~u : (u | 0x80000000u);
}
__device__ __forceinline__ float dec_f(unsigned u){
    unsigned b = (u & 0x80000000u) ? (u ^ 0x80000000u) : ~u;
    return __uint_as_float(b);
}

// async global->LDS copy of a CONTIGUOUS blob; 512 threads.
// LDS base per instruction is wave-uniform; HW adds lane*16.
__device__ __forceinline__ void gllds_copy(const void* gsrc, void* ldst, int nbytes, int tid)
{
    #pragma unroll
    for (int base = 0; base < 16384; base += 8192) {
        if (base >= nbytes) break;
        const int off = base + tid * 16;
        if (off < nbytes) {
            __builtin_amdgcn_global_load_lds(
                (const __attribute__((address_space(1))) unsigned int*)((const char*)gsrc + off),
                (__attribute__((address_space(3))) unsigned int*)((char*)ldst + base + (tid & ~63) * 16),
                16, 0, 0);
        }
    }
}

// ---------------- kernPJ: proj (padded [296][72]) + Wq/Wk/Wv + Wo -> bf16 ws ----------
__launch_bounds__(256)
__global__ void kernPJ(const float* __restrict__ proj,
                       const float* __restrict__ Wq, const float* __restrict__ Wk,
                       const float* __restrict__ Wv, const float* __restrict__ Wo,
                       u16* __restrict__ projb, u16* __restrict__ wqb,
                       u16* __restrict__ wkb, u16* __restrict__ wvb,
                       u16* __restrict__ wob_ws, unsigned* __restrict__ kmax_u)
{
    const int i = blockIdx.x * 256 + threadIdx.x;
    if (i == 0) *kmax_u = 0x007FFFFFu;                  // enc(-inf)
    if (i < PROWS * 9) {
        const int row = i / 9, gi = i % 9, c8 = gi * 8;
        us4 lo = (us4)0, hi = (us4)0;
        if (row < MF && gi < 8) {
            const float* s = proj + (size_t)row * 64 + c8;
            float4 x0 = *(const float4*)s, x1 = *(const float4*)(s + 4);
            lo[0]=f2bf(x0.x); lo[1]=f2bf(x0.y); lo[2]=f2bf(x0.z); lo[3]=f2bf(x0.w);
            hi[0]=f2bf(x1.x); hi[1]=f2bf(x1.y); hi[2]=f2bf(x1.z); hi[3]=f2bf(x1.w);
        }
        *(us4*)(projb + row * 72 + c8)     = lo;
        *(us4*)(projb + row * 72 + c8 + 4) = hi;
    } else if (i < PROWS * 9 + 3 * 4096) {
        const int j = i - PROWS * 9;
        const int mat = j >> 12;
        const int r = (j & 4095) >> 3, d8 = (j & 7) * 8;
        const float* W = (mat == 0) ? Wq : (mat == 1) ? Wk : Wv;
        u16* dst       = (mat == 0) ? wqb : (mat == 1) ? wkb : wvb;
        const float* s = W + (size_t)r * 64 + d8;
        float4 x0 = *(const float4*)s, x1 = *(const float4*)(s + 4);
        us4 lo, hi;
        lo[0]=f2bf(x0.x); lo[1]=f2bf(x0.y); lo[2]=f2bf(x0.z); lo[3]=f2bf(x0.w);
        hi[0]=f2bf(x1.x); hi[1]=f2bf(x1.y); hi[2]=f2bf(x1.z); hi[3]=f2bf(x1.w);
        *(us4*)(dst + (size_t)r * 64 + d8)     = lo;
        *(us4*)(dst + (size_t)r * 64 + d8 + 4) = hi;
    } else if (i < PROWS * 9 + 3 * 4096 + 4096) {
        const int j = i - (PROWS * 9 + 3 * 4096);       // Wo: 64 rows x 512 cols
        const int r = j >> 6, c8 = (j & 63) * 8;
        const float* s = Wo + (size_t)r * 512 + c8;
        float4 x0 = *(const float4*)s, x1 = *(const float4*)(s + 4);
        us4 lo, hi;
        lo[0]=f2bf(x0.x); lo[1]=f2bf(x0.y); lo[2]=f2bf(x0.z); lo[3]=f2bf(x0.w);
        hi[0]=f2bf(x1.x); hi[1]=f2bf(x1.y); hi[2]=f2bf(x1.z); hi[3]=f2bf(x1.w);
        *(us4*)(wob_ws + (size_t)r * 512 + c8)     = lo;
        *(us4*)(wob_ws + (size_t)r * 512 + c8 + 4) = hi;
    }
}

// bf16 tile copy (kernH): src rows (64 wide) -> LDS [nrows][72]
__device__ __forceinline__ void copy_rows72(const u16* __restrict__ src, u16* dst,
                                            int m0, int nrows, int tid, int nthr)
{
    for (int i = tid; i < nrows * 8; i += nthr) {
        int mi = i >> 3, d8 = (i & 7) * 8;
        *(short8*)(dst + mi * 72 + d8) =
            *(const short8*)(src + (size_t)(m0 + mi) * 64 + d8);
    }
}

// ---------------- kernH: head projections -> bf16 ws (+ diag for q,k) ----------------
__launch_bounds__(256)
__global__ void kernH(const float* __restrict__ qin, const float* __restrict__ kin,
                      const float* __restrict__ vin,
                      const u16* __restrict__ wqb, const float* __restrict__ bq,
                      const u16* __restrict__ wkb, const float* __restrict__ bk,
                      const u16* __restrict__ wvb, const float* __restrict__ bv,
                      u16* __restrict__ qh, u16* __restrict__ kh, u16* __restrict__ vh,
                      float* __restrict__ dqw, float* __restrict__ dkw)
{
    extern __shared__ char smh[];
    u16*   xb   = (u16*)smh;             // [128][72]  18432
    u16*   wb   = (u16*)(smh + 18432);   // [64][72]    9216
    float* bsh  = (float*)(smh + 27648); // [64]         256
    u16*   hout = (u16*)(smh + 27904);   // [128][72]  18432  -> 46336

    const int tid = threadIdx.x;
    const int iv  = blockIdx.y;
    const int r0  = blockIdx.x * 128;
    const float* src  = (iv == 0) ? qin : (iv == 1) ? kin : vin;
    const u16*   Wb   = (iv == 0) ? wqb : (iv == 1) ? wkb : wvb;
    const float* bias = (iv == 0) ? bq  : (iv == 1) ? bk  : bv;
    u16*   outp  = (iv == 0) ? qh : (iv == 1) ? kh : vh;
    float* diagp = (iv == 0) ? dqw : (iv == 1) ? dkw : nullptr;
    const float scale = (iv == 0) ? QSC * DN : (iv == 1) ? DN : 1.0f;

    for (int i = tid; i < 128 * 8; i += 256) {
        int r = i >> 3, d8 = (i & 7) * 8;
        const float* s = src + (size_t)(r0 + r) * 64 + d8;
        float4 x0 = *(const float4*)s, x1 = *(const float4*)(s + 4);
        us4 lo, hi;
        lo[0]=f2bf(x0.x); lo[1]=f2bf(x0.y); lo[2]=f2bf(x0.z); lo[3]=f2bf(x0.w);
        hi[0]=f2bf(x1.x); hi[1]=f2bf(x1.y); hi[2]=f2bf(x1.z); hi[3]=f2bf(x1.w);
        *(us4*)(xb + r * 72 + d8)     = lo;
        *(us4*)(xb + r * 72 + d8 + 4) = hi;
    }

    const int c = tid & 15, g = (tid >> 4) & 3, w = tid >> 6;

    for (int h = 0; h < NHEAD; ++h) {
        __syncthreads();
        copy_rows72(Wb, wb, h * 64, 64, tid, 256);
        if (tid < 64) bsh[tid] = bias[h * 64 + tid];
        __syncthreads();

        #pragma unroll
        for (int mi = 0; mi < 2; ++mi) {
            const int mt = w * 2 + mi;
            short8 a0 = *(const short8*)(xb + (mt * 16 + c) * 72 + g * 8);
            short8 a1 = *(const short8*)(xb + (mt * 16 + c) * 72 + 32 + g * 8);
            float sq[4] = {0.f, 0.f, 0.f, 0.f};
            #pragma unroll
            for (int nt = 0; nt < 4; ++nt) {
                short8 b0 = *(const short8*)(wb + (nt * 16 + c) * 72 + g * 8);
                short8 b1 = *(const short8*)(wb + (nt * 16 + c) * 72 + 32 + g * 8);
                f32x4 acc = 0;
                acc = MFMA16(a0, b0, acc);
                acc = MFMA16(a1, b1, acc);
                const float bv2 = bsh[nt * 16 + c];
                #pragma unroll
                for (int r = 0; r < 4; ++r) {
                    float y = (acc[r] + bv2) * scale;
                    sq[r] = fmaf(y, y, sq[r]);
                    hout[(mt * 16 + g * 4 + r) * 72 + nt * 16 + c] = f2bf(y);
                }
            }
            if (diagp) {
                #pragma unroll
                for (int r = 0; r < 4; ++r) {
                    #pragma unroll
                    for (int off = 1; off < 16; off <<= 1) sq[r] += __shfl_xor(sq[r], off);
                    if (c == 0) {
                        int rr = r0 + mt * 16 + g * 4 + r;
                        int t = rr >> 4, bbb = rr & 15;
                        diagp[((size_t)(bbb * 8 + h)) * T_LEN + t] = 0.5f * sq[r];
                    }
                }
            }
        }
        __syncthreads();
        for (int i = tid; i < 128 * 8; i += 256) {
            int r = i >> 3, d8 = (i & 7) * 8;
            int rr = r0 + r, t = rr >> 4, bbb = rr & 15;
            *(short8*)(outp + ((size_t)(bbb * 8 + h) * T_LEN + t) * 64 + d8) =
                *(const short8*)(hout + r * 72 + d8);
        }
    }
}

// ---------------- kernA: unnormalized SsegT (chunk-major) + kmax; gllds staging -------
__launch_bounds__(512, 4)
__global__ void kernA(const u16* __restrict__ kh, const u16* __restrict__ vh,
                      const float* __restrict__ diagk, const u16* __restrict__ projb,
                      unsigned* __restrict__ kmax_u, u16* __restrict__ SsegT)
{
    extern __shared__ char sma[];
    u16* khb = (u16*)sma;            // [128][64] 16384 (gllds, contiguous)
    u16* vTb = (u16*)(sma + 16384);  // [80][136] 21760
    u16* pjb = (u16*)(sma + 38144);  // [96+][72] 14336 (gllds)
    u16* kfT = (u16*)(sma + 52480);  // [96][136] 26112   -> 78592
    __shared__ float red[8];

    const int tid = threadIdx.x;
    const int bh = blockIdx.x, seg = blockIdx.y, t0 = seg * SC;
    const int c = tid & 15, g = (tid >> 4) & 3, w = tid >> 6;
    const size_t sbN = ((size_t)bh * NSEG + seg) * SEG_ELE;
    const size_t hbase = ((size_t)bh * T_LEN + t0) * 64;

    gllds_copy(kh + hbase, khb, 16384, tid);
    gllds_copy(projb, pjb, 14336, tid);

    // vT transpose (vectorized reads): vT[e][s] = vh[t0+s][e]; row 64 = ones; 65..79 = 0
    for (int i = tid; i < 128 * 8; i += 512) {
        int s = i >> 3, e8 = (i & 7) * 8;
        short8 vv = *(const short8*)(vh + hbase + (size_t)s * 64 + e8);
        #pragma unroll
        for (int j = 0; j < 8; ++j) vTb[(e8 + j) * 136 + s] = (u16)vv[j];
    }
    if (tid < 128) vTb[64 * 136 + tid] = 0x3F80;   // bf16(1.0)
    for (int i = tid; i < 15 * 128; i += 512) {
        int r = i >> 7, s = i & 127;
        vTb[(65 + r) * 136 + s] = 0;
    }
    float dk2[4];
    #pragma unroll
    for (int r = 0; r < 4; ++r)
        dk2[r] = -diagk[(size_t)bh * T_LEN + t0 + w * 16 + g * 4 + r] * L2E;  // no kmax
    __syncthreads();                                 // khb/pjb(0) landed; vTb visible

    short8 ak0 = *(const short8*)(khb + (w * 16 + c) * 64 + g * 8);
    short8 ak1 = *(const short8*)(khb + (w * 16 + c) * 64 + 32 + g * 8);

    float kmx = -3.0e38f;

    for (int ch = 0; ch < 3; ++ch) {
        const int mbase = ch * CH;
        // eu features -> kfT (transposed); m==MF -> 1; other m>=MF -> 0; track dd max
        #pragma unroll
        for (int nt = 0; nt < 6; ++nt) {
            short8 b0 = *(const short8*)(pjb + (nt * 16 + c) * 72 + g * 8);
            short8 b1 = *(const short8*)(pjb + (nt * 16 + c) * 72 + 32 + g * 8);
            f32x4 dd = 0;
            dd = MFMA16(ak0, b0, dd);
            dd = MFMA16(ak1, b1, dd);
            const int m = mbase + nt * 16 + c;
            us4 kw;
            #pragma unroll
            for (int r = 0; r < 4; ++r) {
                float eu = __builtin_amdgcn_exp2f(fmaf(dd[r], L2E, dk2[r]));
                float kv = (m < MF) ? eu : ((m == MF) ? 1.0f : 0.f);
                kw[r] = f2bf(kv);
            }
            if (m < MF)
                kmx = fmaxf(kmx, fmaxf(fmaxf(dd[0], dd[1]), fmaxf(dd[2], dd[3])));
            *(us4*)(kfT + (nt * 16 + c) * 136 + w * 16 + g * 4) = kw;
        }
        __syncthreads();                             // kfT visible
        if (ch < 2)                                  // pjb dead -> async next chunk
            gllds_copy(projb + (size_t)(ch + 1) * CH * 72, pjb, 14336, tid);
        // D[m][e] = sum_s kfT[m][s] * vT[e][s]; store chunk-major [65][96]
        for (int tt = w; tt < 30; tt += 8) {
            const int mt = tt / 5, nt = tt % 5;
            f32x4 acc = 0;
            #pragma unroll
            for (int ks = 0; ks < 4; ++ks) {
                short8 a = *(const short8*)(kfT + (mt * 16 + c) * 136 + ks * 32 + g * 8);
                short8 b = *(const short8*)(vTb + (nt * 16 + c) * 136 + ks * 32 + g * 8);
                acc = MFMA16(a, b, acc);
            }
            const int e = nt * 16 + c;
            const int mloc = mt * 16 + g * 4;
            if (e <= 64) {
                us4 sw;
                #pragma unroll
                for (int r = 0; r < 4; ++r) sw[r] = f2bf(acc[r]);
                *(us4*)(SsegT + sbN + (size_t)ch * CH_ELE + (size_t)e * 96 + mloc) = sw;
            }
        }
        if (ch < 2) __syncthreads();                 // kfT reads done; pjb(ch+1) landed
    }

    // kmax reduction
    #pragma unroll
    for (int off = 1; off < 64; off <<= 1) kmx = fmaxf(kmx, __shfl_xor(kmx, off));
    if ((tid & 63) == 0) red[w] = kmx;
    __syncthreads();
    if (tid == 0) {
        float m8 = red[0];
        #pragma unroll
        for (int j = 1; j < 8; ++j) m8 = fmaxf(m8, red[j]);
        atomicMax(kmax_u, enc_f(m8));
    }
}

// ---------------- kernB: exclusive prefix + NORMALIZE (chunk-major layout) ------------
__launch_bounds__(512)
__global__ void kernB(u16* __restrict__ SsegT, const unsigned* __restrict__ kmax_u)
{
    __shared__ float vsl[NSEG][33];
    const int tid = threadIdx.x;
    const int bh = blockIdx.x, eh = blockIdx.y;
    const int nrows = eh ? 33 : 32;
    const int per_ch = nrows * 12;
    const int nch = 3 * per_ch;
    const float kmax = dec_f(*kmax_u);
    const float alpha = RATIO * __builtin_amdgcn_exp2f(-kmax * L2E);
    const float beta  = RATIO * EPSK;

    // pre-load raw Vsum column (chunk 2, mloc 74) for all segments BEFORE any write
    for (int i = tid; i < NSEG * nrows; i += 512) {
        const int s = i / nrows, er = i % nrows;
        vsl[s][er] = bf2f(SsegT[((size_t)bh * NSEG + s) * SEG_ELE + 2 * CH_ELE
                                + (size_t)(eh * 32 + er) * 96 + 74]);
    }
    __syncthreads();

    int idxs[3] = { tid, tid + 512, tid + 1024 };
    int chs[3], ers[3], m8s[3];
    bool act[3];
    #pragma unroll
    for (int k = 0; k < 3; ++k) {
        act[k] = idxs[k] < nch;
        int id = act[k] ? idxs[k] : 0;
        chs[k] = id / per_ch;
        int rem = id % per_ch;
        ers[k] = rem / 12;
        m8s[k] = (rem % 12) * 8;
    }
    float A0[8], A1[8], A2[8];
    float V0 = 0.f, V1 = 0.f, V2 = 0.f;
    #pragma unroll
    for (int j = 0; j < 8; ++j) { A0[j] = 0.f; A1[j] = 0.f; A2[j] = 0.f; }

    for (int s = 0; s < NSEG; ++s) {
        const size_t segb = ((size_t)bh * NSEG + s) * SEG_ELE;
        {
            const size_t gi = segb + (size_t)chs[0] * CH_ELE
                              + (size_t)(eh * 32 + ers[0]) * 96 + m8s[0];
            short8 v = *(const short8*)(SsegT + gi);
            short8 o;
            const float bv = beta * V0;
            #pragma unroll
            for (int j = 0; j < 8; ++j) {
                o[j] = (short)f2bf(fmaf(alpha, A0[j], bv));
                A0[j] += bf2f((u16)v[j]);
            }
            *(short8*)(SsegT + gi) = o;
            V0 += vsl[s][ers[0]];
        }
        if (act[1]) {
            const size_t gi = segb + (size_t)chs[1] * CH_ELE
                              + (size_t)(eh * 32 + ers[1]) * 96 + m8s[1];
            short8 v = *(const short8*)(SsegT + gi);
            short8 o;
            const float bv = beta * V1;
            #pragma unroll
            for (int j = 0; j < 8; ++j) {
                o[j] = (short)f2bf(fmaf(alpha, A1[j], bv));
                A1[j] += bf2f((u16)v[j]);
            }
            *(short8*)(SsegT + gi) = o;
            V1 += vsl[s][ers[1]];
        }
        if (act[2]) {
            const size_t gi = segb + (size_t)chs[2] * CH_ELE
                              + (size_t)(eh * 32 + ers[2]) * 96 + m8s[2];
            short8 v = *(const short8*)(SsegT + gi);
            short8 o;
            const float bv = beta * V2;
            #pragma unroll
            for (int j = 0; j < 8; ++j) {
                o[j] = (short)f2bf(fmaf(alpha, A2[j], bv));
                A2[j] += bf2f((u16)v[j]);
            }
            *(short8*)(SsegT + gi) = o;
            V2 += vsl[s][ers[2]];
        }
    }
}

// ---------------- kernC: main attention (2 blocks/CU; gllds-pipelined staging) --------
__launch_bounds__(512, 4)
__global__ void kernC(const u16* __restrict__ qh, const u16* __restrict__ kh,
                      const u16* __restrict__ vh,
                      const float* __restrict__ diagq, const float* __restrict__ diagk,
                      const u16* __restrict__ projb, const u16* __restrict__ SsegT,
                      const unsigned* __restrict__ kmax_u, u16* __restrict__ merged)
{
    extern __shared__ char smc[];
    u16*   qfb = (u16*)smc;               // [128][104] 26624
    u16*   kfb = (u16*)(smc + 26624);     // [128][104] 26624 -> 53248
    u16*   pjc = (u16*)(smc + 53248);     // [96+][72]  14336 (gllds) -> 67584
    u16*   STb = (u16*)(smc + 67584);     // [64][96]   12288 (gllds) -> 79872
    float* zsf = (float*)(smc + 79872);   // [320] f32   1280 -> 81152
    u16*   Ab  = (u16*)smc;               // alias: [128][136] 34816
    u16*   vTb = (u16*)(smc + 34816);     // alias: [64][136] 17408 (within qfb/kfb)

    const int tid = threadIdx.x;
    const int bh = blockIdx.x, seg = blockIdx.y;
    const int bb = bh >> 3, hh = bh & 7;
    const int t0 = seg * SC;
    const int c = tid & 15, g = (tid >> 4) & 3, w = tid >> 6;
    const size_t hbase = ((size_t)bh * T_LEN + t0) * 64;
    const size_t sbN = ((size_t)bh * NSEG + seg) * SEG_ELE;
    const float kmax = dec_f(*kmax_u);

    // async chunk-0 tiles
    gllds_copy(projb, pjc, 14336, tid);
    gllds_copy(SsegT + sbN, STb, 12288, tid);

    // stage q,k into qfb/kfb (coalesced) + all 3 z rows (f32, pre-biased with EPSD)
    for (int i = tid; i < 128 * 8; i += 512) {
        int r = i >> 3, d8 = (i & 7) * 8;
        *(short8*)(qfb + r * 104 + d8) = *(const short8*)(qh + hbase + (size_t)r * 64 + d8);
        *(short8*)(kfb + r * 104 + d8) = *(const short8*)(kh + hbase + (size_t)r * 64 + d8);
    }
    if (tid < 288) {
        int chz = tid / 96, ml = tid % 96;
        zsf[tid] = bf2f(SsegT[sbN + (size_t)chz * CH_ELE + Z_OFF + ml]) + EPSD;
    } else if (tid < 320) {
        zsf[tid] = 0.f;
    }
    float dq2[4], dk2[4];
    #pragma unroll
    for (int r = 0; r < 4; ++r) {
        const size_t t = (size_t)bh * T_LEN + t0 + w * 16 + g * 4 + r;
        dq2[r] = fmaf(-diagq[t], L2E, L2R);         // no q-max (validated R5-R15); + log2(RATIO)
        dk2[r] = fmaf(-(diagk[t] + kmax), L2E, L2R);
    }
    __syncthreads();                                 // q/k/zsf visible; pjc0/STb0 landed
    const int arow = w * 16 + c;
    short8 aq0 = *(const short8*)(qfb + arow * 104 + g * 8);
    short8 aq1 = *(const short8*)(qfb + arow * 104 + 32 + g * 8);
    short8 ak0 = *(const short8*)(kfb + arow * 104 + g * 8);
    short8 ak1 = *(const short8*)(kfb + arow * 104 + 32 + g * 8);

    f32x4 Aacc[8], nacc[4];
    #pragma unroll
    for (int nt = 0; nt < 8; ++nt) Aacc[nt] = 0;
    #pragma unroll
    for (int nt = 0; nt < 4; ++nt) nacc[nt] = 0;
    float pden[4] = {0.f, 0.f, 0.f, 0.f};

    for (int ch = 0; ch < 3; ++ch) {
        const int mb0 = ch * CH;
        if (ch > 0)                                 // STb(ch-1) reads done at loop-end barrier
            gllds_copy(SsegT + sbN + (size_t)ch * CH_ELE, STb, 12288, tid);
        // features (writes qfb/kfb) + den-partial (pre-biased z from LDS f32)
        #pragma unroll
        for (int nt = 0; nt < 6; ++nt) {
            const int m = mb0 + nt * 16 + c;
            short8 b0 = *(const short8*)(pjc + (nt * 16 + c) * 72 + g * 8);
            short8 b1 = *(const short8*)(pjc + (nt * 16 + c) * 72 + 32 + g * 8);
            f32x4 ddq = 0, ddk = 0;
            ddq = MFMA16(aq0, b0, ddq); ddq = MFMA16(aq1, b1, ddq);
            ddk = MFMA16(ak0, b0, ddk); ddk = MFMA16(ak1, b1, ddk);
            const float zl = zsf[m];
            #pragma unroll
            for (int r = 0; r < 4; ++r) {
                float qv = __builtin_amdgcn_exp2f(fmaf(ddq[r], L2E, dq2[r])) + RB;
                float kv = __builtin_amdgcn_exp2f(fmaf(ddk[r], L2E, dk2[r])) + RB;
                if (m >= MF) { qv = 0.f; kv = 0.f; }
                pden[r] = fmaf(qv, zl, pden[r]);
                const int row = w * 16 + g * 4 + r;
                qfb[row * 104 + nt * 16 + c] = f2bf(qv);
                kfb[row * 104 + nt * 16 + c] = f2bf(kv);
            }
        }
        __syncthreads();                            // features visible; STb(ch) landed
        if (ch < 2)                                 // pjc(ch) dead -> async next chunk
            gllds_copy(projb + (size_t)(ch + 1) * CH * 72, pjc, 14336, tid);
        short8 af[3];
        #pragma unroll
        for (int ks = 0; ks < 3; ++ks)
            af[ks] = *(const short8*)(qfb + arow * 104 + ks * 32 + g * 8);
        #pragma unroll
        for (int nt = 0; nt < 8; ++nt) {
            #pragma unroll
            for (int ks = 0; ks < 3; ++ks) {
                short8 b = *(const short8*)(kfb + (nt * 16 + c) * 104 + ks * 32 + g * 8);
                Aacc[nt] = MFMA16(af[ks], b, Aacc[nt]);
            }
        }
        #pragma unroll
        for (int nt = 0; nt < 4; ++nt) {
            #pragma unroll
            for (int ks = 0; ks < 3; ++ks) {
                short8 b = *(const short8*)(STb + (nt * 16 + c) * 96 + ks * 32 + g * 8);
                nacc[nt] = MFMA16(af[ks], b, nacc[nt]);
            }
        }
        if (ch < 2) __syncthreads();                // GEMM LDS reads done; pjc(ch+1) landed
    }

    // den = qf.(z_pre+EPSD) + rowsum(masked A)
    float den[4], rs[4] = {0.f, 0.f, 0.f, 0.f};
    #pragma unroll
    for (int r = 0; r < 4; ++r) {
        #pragma unroll
        for (int off = 1; off < 16; off <<= 1) pden[r] += __shfl_xor(pden[r], off);
        den[r] = pden[r];
    }
    #pragma unroll
    for (int nt = 0; nt < 8; ++nt) {
        #pragma unroll
        for (int r = 0; r < 4; ++r) {
            const int row = w * 16 + g * 4 + r, sc2 = nt * 16 + c;
            float av = (sc2 < row) ? Aacc[nt][r] : 0.f;
            Aacc[nt][r] = av;
            rs[r] += av;
        }
    }
    #pragma unroll
    for (int r = 0; r < 4; ++r) {
        #pragma unroll
        for (int off = 1; off < 16; off <<= 1) rs[r] += __shfl_xor(rs[r], off);
        den[r] += rs[r];
    }

    __syncthreads();                                // all chunk reads done
    #pragma unroll
    for (int nt = 0; nt < 8; ++nt)
        #pragma unroll
        for (int r = 0; r < 4; ++r)
            Ab[(w * 16 + g * 4 + r) * 136 + nt * 16 + c] = f2bf(Aacc[nt][r]);
    for (int i = tid; i < 128 * 8; i += 512) {
        int s = i >> 3, e8 = (i & 7) * 8;
        short8 vv = *(const short8*)(vh + hbase + (size_t)s * 64 + e8);
        #pragma unroll
        for (int j = 0; j < 8; ++j) vTb[(e8 + j) * 136 + s] = (u16)vv[j];
    }
    __syncthreads();

    short8 aab[4];
    #pragma unroll
    for (int ks = 0; ks < 4; ++ks)
        aab[ks] = *(const short8*)(Ab + arow * 136 + ks * 32 + g * 8);
    #pragma unroll
    for (int nt = 0; nt < 4; ++nt) {
        #pragma unroll
        for (int ks = 0; ks < 4; ++ks) {
            short8 b = *(const short8*)(vTb + (nt * 16 + c) * 136 + ks * 32 + g * 8);
            nacc[nt] = MFMA16(aab[ks], b, nacc[nt]);
        }
    }

    #pragma unroll
    for (int r = 0; r < 4; ++r) {
        const float inv = 1.0f / den[r];
        const int t = t0 + w * 16 + g * 4 + r;
        #pragma unroll
        for (int nt = 0; nt < 4; ++nt)
            merged[((size_t)bb * T_LEN + t) * 512 + hh * 64 + nt * 16 + c] =
                f2bf(nacc[nt][r] * inv);
    }
}

// ---------------- kernD: output projection + transpose (bf16 Wo from ws) --------------
__launch_bounds__(256)
__global__ void kernD(const u16* __restrict__ merged, const u16* __restrict__ wob_ws,
                      const float* __restrict__ bo, float* __restrict__ out)
{
    extern __shared__ char smd[];
    u16* mb  = (u16*)smd;            // [128][136] 34816
    u16* wob = (u16*)(smd + 34816);  // [64][136]  17408

    const int tid = threadIdx.x;
    const int r0 = blockIdx.x * 128;
    const int c = tid & 15, g = (tid >> 4) & 3, w = tid >> 6;

    f32x4 acc[2][4];
    #pragma unroll
    for (int mi = 0; mi < 2; ++mi)
        #pragma unroll
        for (int nt = 0; nt < 4; ++nt) acc[mi][nt] = 0;

    for (int kc = 0; kc < 4; ++kc) {
        __syncthreads();
        for (int i = tid; i < 128 * 16; i += 256) {
            int r = i >> 4, d8 = (i & 15) * 8;
            *(short8*)(mb + r * 136 + d8) =
                *(const short8*)(merged + (size_t)(r0 + r) * 512 + kc * 128 + d8);
        }
        for (int i = tid; i < 64 * 16; i += 256) {
            int r = i >> 4, d8 = (i & 15) * 8;
            *(short8*)(wob + r * 136 + d8) =
                *(const short8*)(wob_ws + (size_t)r * 512 + kc * 128 + d8);
        }
        __syncthreads();
        #pragma unroll
        for (int mi = 0; mi < 2; ++mi) {
            const int mt = w * 2 + mi;
            #pragma unroll
            for (int ks = 0; ks < 4; ++ks) {
                short8 a = *(const short8*)(mb + (mt * 16 + c) * 136 + ks * 32 + g * 8);
                #pragma unroll
                for (int nt = 0; nt < 4; ++nt) {
                    short8 b = *(const short8*)(wob + (nt * 16 + c) * 136 + ks * 32 + g * 8);
                    acc[mi][nt] = MFMA16(a, b, acc[mi][nt]);
                }
            }
        }
    }
    #pragma unroll
    for (int mi = 0; mi < 2; ++mi) {
        const int mt = w * 2 + mi;
        #pragma unroll
        for (int nt = 0; nt < 4; ++nt) {
            const float bv2 = bo[nt * 16 + c];
            #pragma unroll
            for (int r = 0; r < 4; ++r) {
                int rg = r0 + mt * 16 + g * 4 + r;
                int bbb = rg >> 11, t = rg & (T_LEN - 1);
                out[((size_t)t * BSZ + bbb) * 64 + nt * 16 + c] = acc[mi][nt][r] + bv2;
            }
        }
    }
}

extern "C" void kernel_launch(void* const* d_in, const int* in_sizes, int n_in,
                              void* d_out, int out_size, void* d_ws, size_t ws_size,
                              hipStream_t stream)
{
    (void)in_sizes; (void)n_in; (void)out_size; (void)ws_size;
    const float* qin  = (const float*)d_in[0];
    const float* kin  = (const float*)d_in[1];
    const float* vin  = (const float*)d_in[2];
    const float* Wq   = (const float*)d_in[3];
    const float* bq   = (const float*)d_in[4];
    const float* Wk   = (const float*)d_in[5];
    const float* bk   = (const float*)d_in[6];
    const float* Wv   = (const float*)d_in[7];
    const float* bv   = (const float*)d_in[8];
    const float* Wo   = (const float*)d_in[9];
    const float* bo   = (const float*)d_in[10];
    const float* proj = (const float*)d_in[11];

    char* p = (char*)d_ws;
    unsigned* kmax_u = (unsigned*)p;           p += 256;
    u16* projb = (u16*)p;  p += (size_t)PROWS * 72 * 2;                 // 42,624 B
    u16* wqb = (u16*)p;    p += (size_t)512 * 64 * 2;
    u16* wkb = (u16*)p;    p += (size_t)512 * 64 * 2;
    u16* wvb = (u16*)p;    p += (size_t)512 * 64 * 2;
    u16* wob_ws = (u16*)p; p += (size_t)64 * 512 * 2;
    u16* qh_ws = (u16*)p;  p += (size_t)BH * T_LEN * 64 * 2;
    u16* kh_ws = (u16*)p;  p += (size_t)BH * T_LEN * 64 * 2;
    u16* vh_ws = (u16*)p;  p += (size_t)BH * T_LEN * 64 * 2;
    float* diagq = (float*)p; p += (size_t)BH * T_LEN * 4;
    float* diagk = (float*)p; p += (size_t)BH * T_LEN * 4;
    u16* SsegT = (u16*)p;  p += (size_t)BH * NSEG * SEG_ELE * 2 + 1024;  // 76.7 MB
    u16* merged = (u16*)p;                                               // 33.5 MB

    const int LDS_H = 46336;
    const int LDS_A = 78592;
    const int LDS_C = 81152;
    const int LDS_D = 52224;
    (void)hipFuncSetAttribute((const void*)kernA, hipFuncAttributeMaxDynamicSharedMemorySize, LDS_A);
    (void)hipFuncSetAttribute((const void*)kernC, hipFuncAttributeMaxDynamicSharedMemorySize, LDS_C);

    kernPJ<<<75, 256, 0, stream>>>(proj, Wq, Wk, Wv, Wo, projb, wqb, wkb, wvb, wob_ws, kmax_u);
    kernH<<<dim3(256, 3), 256, LDS_H, stream>>>(qin, kin, vin, wqb, bq, wkb, bk, wvb, bv,
                                                qh_ws, kh_ws, vh_ws, diagq, diagk);
    kernA<<<dim3(BH, NSEG), 512, LDS_A, stream>>>(kh_ws, vh_ws, diagk, projb, kmax_u, SsegT);
    kernB<<<dim3(BH, 2), 512, 0, stream>>>(SsegT, kmax_u);
    kernC<<<dim3(BH, NSEG), 512, LDS_C, stream>>>(qh_ws, kh_ws, vh_ws, diagq, diagk,
                                                  projb, SsegT, kmax_u, merged);
    kernD<<<256, 256, LDS_D, stream>>>(merged, wob_ws, bo, (float*)d_out);
}